// Round 1
// baseline (9622.266 us; speedup 1.0000x reference)
//
#include <hip/hip_runtime.h>
#include <hip/hip_bf16.h>
#include <cstdint>

// ---------------------------------------------------------------------------
// 2-layer LSTM (B=512, T=128, F=64, H=1024) + dense sigmoid head.
// fp16 MFMA GEMMs w/ fp32 accumulation, fused gate epilogue.
// ---------------------------------------------------------------------------

typedef __attribute__((ext_vector_type(8))) _Float16 half8;
typedef __attribute__((ext_vector_type(4))) _Float16 half4v;
typedef __attribute__((ext_vector_type(4))) float    float4v;

#define AS1 __attribute__((address_space(1)))
#define AS3 __attribute__((address_space(3)))

__device__ __forceinline__ void g2l16(const void* gptr, void* lptr) {
    // async global->LDS, 16B/lane; LDS dest is wave-uniform base + lane*16
    __builtin_amdgcn_global_load_lds((const AS1 void*)gptr, (AS3 void*)lptr, 16, 0, 0);
}

__device__ __forceinline__ float sigf(float x) { return 1.0f / (1.0f + __expf(-x)); }
__device__ __forceinline__ float tanhfast(float x) { return 2.0f * sigf(2.0f * x) - 1.0f; }

// ---------------------------------------------------------------------------
// Fused LSTM step:  z = [A1|A2] @ [B1T|B2T]^T + bias ; gates ; c,h update.
// A1: (512, KA) row-major f16, row stride a1_stride, column base a1_off
// A2: (512, KB) row-major f16, row stride 1024 (the recurrent h)
// B1T/B2T: (4096, K) f16, row = gate-major output column (g*1024 + n)
// Block tile: 64 rows x 32 hidden units x 4 gates. Grid (32, 8): n-tile on x
// so the 8 m-blocks sharing a B slice map to one XCD (id % 8 const).
// ---------------------------------------------------------------------------
__global__ __launch_bounds__(256) void lstm_step(
    const _Float16* __restrict__ A1, long a1_stride, long a1_off, int KA,
    const _Float16* __restrict__ B1T, int ldb1,
    const _Float16* __restrict__ A2,
    const _Float16* __restrict__ B2T, int KB,
    const float* __restrict__ bias,
    float* __restrict__ c_state,
    _Float16* __restrict__ h_out)
{
    __shared__ __align__(16) _Float16 Alds[64 * 64];       // [kc][row][8]
    __shared__ __align__(16) _Float16 Blds[4][32 * 64];    // per gate [kc][n][8]

    const int tid = threadIdx.x;
    const int w   = tid >> 6;      // wave 0..3
    const int l   = tid & 63;
    const int q   = l >> 4;        // quad 0..3
    const int c16 = l & 15;
    const int mh  = w & 1;         // 32-row half
    const int nh  = w >> 1;        // 16-unit half

    const int m0 = blockIdx.y * 64;
    const int n0 = blockIdx.x * 32;

    float4v acc[4][2] = {};        // [gate][m-subtile]

    const int KT = (KA + KB) >> 6; // BK = 64

    for (int kt = 0; kt < KT; ++kt) {
        const int kbase = kt << 6;
        __syncthreads();   // previous iter's ds_reads complete before overwrite

        // ---- stage A tile (64 rows x 64 k): 8 chunk-column instrs ----
        const _Float16* Ap;  long arow, aoff;
        if (kbase < KA) { Ap = A1; arow = a1_stride; aoff = a1_off + kbase; }
        else            { Ap = A2; arow = 1024;      aoff = kbase - KA; }
        {
            const _Float16* g0 = Ap + (long)(m0 + l) * arow + aoff;
            g2l16(g0 + (long)w * 8,       &Alds[(w)     * 512]);
            g2l16(g0 + (long)(w + 4) * 8, &Alds[(w + 4) * 512]);
        }
        // ---- stage B tiles: wave w loads gate w (32 n x 64 k, 4 instrs) ----
        {
            const _Float16* Bp; long ldb, bcol;
            if (kbase < KA) { Bp = B1T; ldb = ldb1; bcol = kbase; }
            else            { Bp = B2T; ldb = 1024; bcol = kbase - KA; }
            const int bn   = l & 31;
            const int bkc0 = l >> 5;   // 0/1
            const _Float16* gb = Bp + (long)(w * 1024 + n0 + bn) * ldb + bcol;
            g2l16(gb + (long)(0 + bkc0) * 8, &Blds[w][0 * 512]);
            g2l16(gb + (long)(2 + bkc0) * 8, &Blds[w][1 * 512]);
            g2l16(gb + (long)(4 + bkc0) * 8, &Blds[w][2 * 512]);
            g2l16(gb + (long)(6 + bkc0) * 8, &Blds[w][3 * 512]);
        }
        __syncthreads();   // implicit vmcnt(0): staging complete

        // ---- compute: 16 MFMAs / wave ----
#pragma unroll
        for (int K0 = 0; K0 < 2; ++K0) {
            const int kc = K0 * 4 + q;
            half8 af0 = *(const half8*)&Alds[(kc * 64 + mh * 32 + 0  + c16) * 8];
            half8 af1 = *(const half8*)&Alds[(kc * 64 + mh * 32 + 16 + c16) * 8];
#pragma unroll
            for (int g = 0; g < 4; ++g) {
                half8 bf = *(const half8*)&Blds[g][(kc * 32 + nh * 16 + c16) * 8];
                acc[g][0] = __builtin_amdgcn_mfma_f32_16x16x32_f16(af0, bf, acc[g][0], 0, 0, 0);
                acc[g][1] = __builtin_amdgcn_mfma_f32_16x16x32_f16(af1, bf, acc[g][1], 0, 0, 0);
            }
        }
    }

    // ---- fused gate epilogue: D row = quad*4+i, col = lane&15 ----
    const int n = n0 + nh * 16 + c16;
    const float bi = bias[n];
    const float bff = bias[1024 + n];
    const float bg = bias[2048 + n];
    const float bo = bias[3072 + n];
#pragma unroll
    for (int mt = 0; mt < 2; ++mt) {
#pragma unroll
        for (int i = 0; i < 4; ++i) {
            const int m = m0 + mh * 32 + mt * 16 + q * 4 + i;
            const float zi = acc[0][mt][i] + bi;
            const float zf = acc[1][mt][i] + bff;
            const float zg = acc[2][mt][i] + bg;
            const float zo = acc[3][mt][i] + bo;
            const float ig = sigf(zi);
            const float fg = sigf(zf);
            const float gg = tanhfast(zg);
            const float og = sigf(zo);
            const size_t idx = (size_t)m * 1024 + n;
            const float cc = fg * c_state[idx] + ig * gg;
            c_state[idx] = cc;
            h_out[idx] = (_Float16)(og * tanhfast(cc));
        }
    }
}

// ---------------------------------------------------------------------------
// fp32 (R,C) -> f16 (C,R) tiled transpose-convert
// ---------------------------------------------------------------------------
__global__ void transpose_cvt(const float* __restrict__ in, _Float16* __restrict__ out,
                              int R, int C)
{
    __shared__ float tile[32][33];
    const int c0 = blockIdx.x * 32, r0 = blockIdx.y * 32;
    const int tx = threadIdx.x, ty = threadIdx.y;   // (32, 8)
#pragma unroll
    for (int j = ty; j < 32; j += 8) {
        int r = r0 + j, c = c0 + tx;
        tile[j][tx] = (r < R && c < C) ? in[(size_t)r * C + c] : 0.0f;
    }
    __syncthreads();
#pragma unroll
    for (int j = ty; j < 32; j += 8) {
        int c = c0 + j, r = r0 + tx;
        if (c < C && r < R) out[(size_t)c * R + r] = (_Float16)tile[tx][j];
    }
}

__global__ void cvt_f16(const float* __restrict__ in, _Float16* __restrict__ out, int n)
{
    int i = (blockIdx.x * blockDim.x + threadIdx.x) * 4;
    if (i + 3 < n) {
        float4 v = *(const float4*)(in + i);
        half4v h = { (_Float16)v.x, (_Float16)v.y, (_Float16)v.z, (_Float16)v.w };
        *(half4v*)(out + i) = h;
    }
}

// ---------------------------------------------------------------------------
// Dense head: out[m] = sigmoid(h2[m,:] . Wd + bd), one wave per row
// ---------------------------------------------------------------------------
__global__ __launch_bounds__(64) void dense_head(const _Float16* __restrict__ h2,
                                                 const float* __restrict__ Wd,
                                                 const float* __restrict__ bd,
                                                 float* __restrict__ out)
{
    const int m = blockIdx.x;
    const int l = threadIdx.x;
    float s = 0.0f;
#pragma unroll
    for (int k = l; k < 1024; k += 64)
        s += (float)h2[(size_t)m * 1024 + k] * Wd[k];
    for (int off = 32; off > 0; off >>= 1) s += __shfl_down(s, off);
    if (l == 0) out[m] = 1.0f / (1.0f + __expf(-(s + bd[0])));
}

// ---------------------------------------------------------------------------

extern "C" void kernel_launch(void* const* d_in, const int* in_sizes, int n_in,
                              void* d_out, int out_size, void* d_ws, size_t ws_size,
                              hipStream_t stream)
{
    const float* x  = (const float*)d_in[0];
    const float* W1 = (const float*)d_in[1];
    const float* U1 = (const float*)d_in[2];
    const float* b1 = (const float*)d_in[3];
    const float* W2 = (const float*)d_in[4];
    const float* U2 = (const float*)d_in[5];
    const float* b2 = (const float*)d_in[6];
    const float* Wd = (const float*)d_in[7];
    const float* bd = (const float*)d_in[8];
    float* out = (float*)d_out;

    char* ws = (char*)d_ws;
    size_t off = 0;
    auto alloc = [&](size_t bytes) {
        char* p = ws + off;
        off = (off + bytes + 255) & ~(size_t)255;
        return p;
    };
    _Float16* xb  = (_Float16*)alloc(512ull * 128 * 64 * 2);   // x as f16 (B,T,F)
    _Float16* W1T = (_Float16*)alloc(4096ull * 64 * 2);        // (4H, F)
    _Float16* U1T = (_Float16*)alloc(4096ull * 1024 * 2);      // (4H, H)
    _Float16* W2T = (_Float16*)alloc(4096ull * 1024 * 2);
    _Float16* U2T = (_Float16*)alloc(4096ull * 1024 * 2);
    _Float16* h1  = (_Float16*)alloc(2ull * 512 * 1024 * 2);   // ping-pong
    _Float16* h2  = (_Float16*)alloc(2ull * 512 * 1024 * 2);
    float*    c1  = (float*)alloc(512ull * 1024 * 4);
    float*    c2  = (float*)alloc(512ull * 1024 * 4);

    // zero initial state (ws is re-poisoned to 0xAA before every launch)
    hipMemsetAsync(c1, 0, 512ull * 1024 * 4, stream);
    hipMemsetAsync(c2, 0, 512ull * 1024 * 4, stream);
    hipMemsetAsync(h1, 0, 512ull * 1024 * 2, stream);  // slot 0
    hipMemsetAsync(h2, 0, 512ull * 1024 * 2, stream);  // slot 0

    cvt_f16<<<4096, 256, 0, stream>>>(x, xb, 512 * 128 * 64);
    dim3 tb(32, 8);
    transpose_cvt<<<dim3(4096 / 32,   64 / 32), tb, 0, stream>>>(W1, W1T,   64, 4096);
    transpose_cvt<<<dim3(4096 / 32, 1024 / 32), tb, 0, stream>>>(U1, U1T, 1024, 4096);
    transpose_cvt<<<dim3(4096 / 32, 1024 / 32), tb, 0, stream>>>(W2, W2T, 1024, 4096);
    transpose_cvt<<<dim3(4096 / 32, 1024 / 32), tb, 0, stream>>>(U2, U2T, 1024, 4096);

    const dim3 sgrid(32, 8);     // (n-tiles, m-tiles): n on x for XCD locality
    const size_t HS = 512ull * 1024;
    for (int t = 0; t < 128; ++t) {
        const int r = t & 1, wr = 1 - r;
        // layer 1: z = x_t@W1 + h1@U1 + b1
        lstm_step<<<sgrid, 256, 0, stream>>>(
            xb, 128 * 64, (long)t * 64, 64, W1T, 64,
            h1 + (size_t)r * HS, U1T, 1024, b1, c1, h1 + (size_t)wr * HS);
        // layer 2: z = h1_t@W2 + h2@U2 + b2
        lstm_step<<<sgrid, 256, 0, stream>>>(
            h1 + (size_t)wr * HS, 1024, 0, 1024, W2T, 1024,
            h2 + (size_t)r * HS, U2T, 1024, b2, c2, h2 + (size_t)wr * HS);
    }
    // final write slot at t=127 is slot 0
    dense_head<<<512, 64, 0, stream>>>(h2, Wd, bd, out);
}

// Round 2
// 4428.041 us; speedup vs baseline: 2.1730x; 2.1730x over previous
//
#include <hip/hip_runtime.h>
#include <hip/hip_bf16.h>
#include <cstdint>

// ---------------------------------------------------------------------------
// 2-layer LSTM (B=512, T=128, F=64, H=1024) + dense sigmoid head.
// fp16 MFMA GEMMs w/ fp32 accumulation, fused gate epilogue.
// R2: pipeline-fused step kernel (layer1 step s + layer2 step s-1 in one
// launch, 512 blocks = 2/CU), coalesced XOR-swizzled global_load_lds staging.
// ---------------------------------------------------------------------------

typedef __attribute__((ext_vector_type(8))) _Float16 half8;
typedef __attribute__((ext_vector_type(4))) _Float16 half4v;
typedef __attribute__((ext_vector_type(4))) float    float4v;

#define AS1 __attribute__((address_space(1)))
#define AS3 __attribute__((address_space(3)))

__device__ __forceinline__ void g2l16(const void* gptr, void* lptr) {
    // async global->LDS, 16B/lane; LDS dest is wave-uniform base + lane*16
    __builtin_amdgcn_global_load_lds((const AS1 void*)gptr, (AS3 void*)lptr, 16, 0, 0);
}

__device__ __forceinline__ float sigf(float x) { return 1.0f / (1.0f + __expf(-x)); }
__device__ __forceinline__ float tanhfast(float x) { return 2.0f * sigf(2.0f * x) - 1.0f; }

static constexpr size_t HS = 512ull * 1024;   // one h ping-pong slot (elems)

// ---------------------------------------------------------------------------
// Fused pipeline step. Launch s (0..128):
//   even blocks: layer1 step t=s      (skip when s==128)
//   odd  blocks: layer2 step t=s-1    (skip when s==0)
// Per role: z = [A1|A2] @ [B1T|B2T]^T + bias ; gates ; c,h update.
// Block tile: 64 rows x 32 hidden units x 4 gates; grid 512 = 2 blocks/CU.
// LDS staging: 8 lanes/row x 128 B contiguous, XOR chunk swizzle
// slot = kc ^ (row&7) applied on the GLOBAL source side (global_load_lds's
// LDS destination is lane-forced base+lane*16), so ds_read_b128 fragment
// reads are bank-conflict-free (2-way = free).
// ---------------------------------------------------------------------------
__global__ __launch_bounds__(256) void fused_step(
    int s,
    const _Float16* __restrict__ xb,
    const _Float16* __restrict__ W1T, const _Float16* __restrict__ U1T,
    const float* __restrict__ b1, float* __restrict__ c1, _Float16* __restrict__ h1,
    const _Float16* __restrict__ W2T, const _Float16* __restrict__ U2T,
    const float* __restrict__ b2, float* __restrict__ c2, _Float16* __restrict__ h2)
{
    __shared__ __align__(16) _Float16 Alds[64 * 64];     // [row][slot*8], slot=kc^(row&7)
    __shared__ __align__(16) _Float16 Blds[4][32 * 64];  // per gate [n][slot*8]

    const int role = blockIdx.x & 1;
    const int idx  = blockIdx.x >> 1;        // 0..255: (m-tile, n-tile)

    const _Float16 *A1, *A2, *B1T, *B2T;
    const float* bias; float* cs; _Float16* ho;
    long a1s, a1o; int KA, ldb1;
    if (role == 0) {                         // ---- layer 1, step t = s ----
        const int t = s; if (t >= 128) return;
        A1 = xb; a1s = 128 * 64; a1o = (long)t * 64; KA = 64;
        B1T = W1T; ldb1 = 64;
        A2 = h1 + (size_t)(t & 1) * HS;      // h1(t-1)
        B2T = U1T; bias = b1; cs = c1;
        ho = h1 + (size_t)(1 - (t & 1)) * HS;
    } else {                                 // ---- layer 2, step t = s-1 ----
        const int t = s - 1; if (t < 0) return;
        A1 = h1 + (size_t)(1 - (t & 1)) * HS;  // h1(t), written this same parity chain
        a1s = 1024; a1o = 0; KA = 1024;
        B1T = W2T; ldb1 = 1024;
        A2 = h2 + (size_t)(t & 1) * HS;      // h2(t-1)
        B2T = U2T; bias = b2; cs = c2;
        ho = h2 + (size_t)(1 - (t & 1)) * HS;
    }

    const int tid = threadIdx.x;
    const int w   = tid >> 6;      // wave 0..3
    const int l   = tid & 63;
    const int q   = l >> 4;        // quad 0..3
    const int c16 = l & 15;
    const int mh  = w & 1;         // 32-row half
    const int nh  = w >> 1;        // 16-unit half

    const int m0 = (idx >> 5) * 64;      // 8 m-tiles
    const int n0 = (idx & 31) * 32;      // 32 n-tiles (x-fastest -> same XCD per n)

    const int lr = l >> 3;         // row-in-group 0..7
    const int lc = l & 7;          // chunk slot 0..7
    const int kcg = lc ^ lr;       // swizzled global chunk this lane fetches

    float4v acc[4][2] = {};        // [gate][m-subtile]

    const int KT = (KA + 1024) >> 6;   // BK = 64 (17 for layer1, 32 for layer2)

    for (int kt = 0; kt < KT; ++kt) {
        const int kbase = kt << 6;
        __syncthreads();   // previous iter's ds_reads complete before overwrite

        // ---- stage A tile (64 rows x 64 k): 8 instrs, 8 rows each ----
        const _Float16* Ap;  long arow, aoff;
        if (kbase < KA) { Ap = A1; arow = a1s;  aoff = a1o + kbase; }
        else            { Ap = A2; arow = 1024; aoff = kbase - KA; }
#pragma unroll
        for (int ii = 0; ii < 2; ++ii) {
            const int i = w + ii * 4;            // group 0..7
            const int row = i * 8 + lr;
            g2l16(Ap + (long)(m0 + row) * arow + aoff + kcg * 8, &Alds[i * 512]);
        }
        // ---- stage B tiles: wave w loads gate w (32 n x 64 k): 4 instrs ----
        {
            const _Float16* Bp; long ldb, bcol;
            if (kbase < KA) { Bp = B1T; ldb = ldb1; bcol = kbase; }
            else            { Bp = B2T; ldb = 1024; bcol = kbase - KA; }
            const _Float16* gb = Bp + (long)(w * 1024 + n0) * ldb + bcol;
#pragma unroll
            for (int i = 0; i < 4; ++i) {
                const int row = i * 8 + lr;
                g2l16(gb + (long)row * ldb + kcg * 8, &Blds[w][i * 512]);
            }
        }
        __syncthreads();   // implicit vmcnt(0): staging complete

        // ---- compute: 16 MFMAs / wave ----
        const int n  = nh * 16 + c16;
        const int m1 = mh * 32 + c16;
        const int m2 = m1 + 16;          // (m2&7)==(m1&7)
#pragma unroll
        for (int K0 = 0; K0 < 2; ++K0) {
            const int kc = K0 * 4 + q;
            const int as = (kc ^ (m1 & 7)) * 8;
            const int bs = (kc ^ (n & 7)) * 8;
            half8 af0 = *(const half8*)&Alds[m1 * 64 + as];
            half8 af1 = *(const half8*)&Alds[m2 * 64 + as];
#pragma unroll
            for (int g = 0; g < 4; ++g) {
                half8 bf = *(const half8*)&Blds[g][n * 64 + bs];
                acc[g][0] = __builtin_amdgcn_mfma_f32_16x16x32_f16(af0, bf, acc[g][0], 0, 0, 0);
                acc[g][1] = __builtin_amdgcn_mfma_f32_16x16x32_f16(af1, bf, acc[g][1], 0, 0, 0);
            }
        }
    }

    // ---- fused gate epilogue: D row = quad*4+i, col = lane&15 ----
    const int n = n0 + nh * 16 + c16;
    const float bi  = bias[n];
    const float bff = bias[1024 + n];
    const float bg  = bias[2048 + n];
    const float bo  = bias[3072 + n];
#pragma unroll
    for (int mt = 0; mt < 2; ++mt) {
#pragma unroll
        for (int i = 0; i < 4; ++i) {
            const int m = m0 + mh * 32 + mt * 16 + q * 4 + i;
            const float zi = acc[0][mt][i] + bi;
            const float zf = acc[1][mt][i] + bff;
            const float zg = acc[2][mt][i] + bg;
            const float zo = acc[3][mt][i] + bo;
            const float ig = sigf(zi);
            const float fg = sigf(zf);
            const float gg = tanhfast(zg);
            const float og = sigf(zo);
            const size_t id2 = (size_t)m * 1024 + n;
            const float cc = fg * cs[id2] + ig * gg;
            cs[id2] = cc;
            ho[id2] = (_Float16)(og * tanhfast(cc));
        }
    }
}

// ---------------------------------------------------------------------------
// fp32 (R,C) -> f16 (C,R) tiled transpose-convert
// ---------------------------------------------------------------------------
__global__ void transpose_cvt(const float* __restrict__ in, _Float16* __restrict__ out,
                              int R, int C)
{
    __shared__ float tile[32][33];
    const int c0 = blockIdx.x * 32, r0 = blockIdx.y * 32;
    const int tx = threadIdx.x, ty = threadIdx.y;   // (32, 8)
#pragma unroll
    for (int j = ty; j < 32; j += 8) {
        int r = r0 + j, c = c0 + tx;
        tile[j][tx] = (r < R && c < C) ? in[(size_t)r * C + c] : 0.0f;
    }
    __syncthreads();
#pragma unroll
    for (int j = ty; j < 32; j += 8) {
        int c = c0 + j, r = r0 + tx;
        if (c < C && r < R) out[(size_t)c * R + r] = (_Float16)tile[tx][j];
    }
}

__global__ void cvt_f16(const float* __restrict__ in, _Float16* __restrict__ out, int n)
{
    int i = (blockIdx.x * blockDim.x + threadIdx.x) * 4;
    if (i + 3 < n) {
        float4 v = *(const float4*)(in + i);
        half4v h = { (_Float16)v.x, (_Float16)v.y, (_Float16)v.z, (_Float16)v.w };
        *(half4v*)(out + i) = h;
    }
}

// ---------------------------------------------------------------------------
// Dense head: out[m] = sigmoid(h2[m,:] . Wd + bd), one wave per row
// ---------------------------------------------------------------------------
__global__ __launch_bounds__(64) void dense_head(const _Float16* __restrict__ h2,
                                                 const float* __restrict__ Wd,
                                                 const float* __restrict__ bd,
                                                 float* __restrict__ out)
{
    const int m = blockIdx.x;
    const int l = threadIdx.x;
    float s = 0.0f;
#pragma unroll
    for (int k = l; k < 1024; k += 64)
        s += (float)h2[(size_t)m * 1024 + k] * Wd[k];
    for (int off = 32; off > 0; off >>= 1) s += __shfl_down(s, off);
    if (l == 0) out[m] = 1.0f / (1.0f + __expf(-(s + bd[0])));
}

// ---------------------------------------------------------------------------

extern "C" void kernel_launch(void* const* d_in, const int* in_sizes, int n_in,
                              void* d_out, int out_size, void* d_ws, size_t ws_size,
                              hipStream_t stream)
{
    const float* x  = (const float*)d_in[0];
    const float* W1 = (const float*)d_in[1];
    const float* U1 = (const float*)d_in[2];
    const float* b1 = (const float*)d_in[3];
    const float* W2 = (const float*)d_in[4];
    const float* U2 = (const float*)d_in[5];
    const float* b2 = (const float*)d_in[6];
    const float* Wd = (const float*)d_in[7];
    const float* bd = (const float*)d_in[8];
    float* out = (float*)d_out;

    char* ws = (char*)d_ws;
    size_t off = 0;
    auto alloc = [&](size_t bytes) {
        char* p = ws + off;
        off = (off + bytes + 255) & ~(size_t)255;
        return p;
    };
    _Float16* xb  = (_Float16*)alloc(512ull * 128 * 64 * 2);   // x as f16 (B,T,F)
    _Float16* W1T = (_Float16*)alloc(4096ull * 64 * 2);        // (4H, F)
    _Float16* U1T = (_Float16*)alloc(4096ull * 1024 * 2);      // (4H, H)
    _Float16* W2T = (_Float16*)alloc(4096ull * 1024 * 2);
    _Float16* U2T = (_Float16*)alloc(4096ull * 1024 * 2);
    _Float16* h1  = (_Float16*)alloc(2ull * 512 * 1024 * 2);   // ping-pong
    _Float16* h2  = (_Float16*)alloc(2ull * 512 * 1024 * 2);
    float*    c1  = (float*)alloc(512ull * 1024 * 4);
    float*    c2  = (float*)alloc(512ull * 1024 * 4);

    // zero initial state (ws is re-poisoned to 0xAA before every launch)
    hipMemsetAsync(c1, 0, 512ull * 1024 * 4, stream);
    hipMemsetAsync(c2, 0, 512ull * 1024 * 4, stream);
    hipMemsetAsync(h1, 0, 512ull * 1024 * 2, stream);  // slot 0 (read at t=0)
    hipMemsetAsync(h2, 0, 512ull * 1024 * 2, stream);  // slot 0

    cvt_f16<<<4096, 256, 0, stream>>>(x, xb, 512 * 128 * 64);
    dim3 tb(32, 8);
    transpose_cvt<<<dim3(4096 / 32,   64 / 32), tb, 0, stream>>>(W1, W1T,   64, 4096);
    transpose_cvt<<<dim3(4096 / 32, 1024 / 32), tb, 0, stream>>>(U1, U1T, 1024, 4096);
    transpose_cvt<<<dim3(4096 / 32, 1024 / 32), tb, 0, stream>>>(W2, W2T, 1024, 4096);
    transpose_cvt<<<dim3(4096 / 32, 1024 / 32), tb, 0, stream>>>(U2, U2T, 1024, 4096);

    // 129 pipelined launches: launch s does layer1(s) + layer2(s-1)
    for (int s = 0; s <= 128; ++s) {
        fused_step<<<512, 256, 0, stream>>>(s, xb,
                                            W1T, U1T, b1, c1, h1,
                                            W2T, U2T, b2, c2, h2);
    }
    // h2(127) lands in slot 0
    dense_head<<<512, 64, 0, stream>>>(h2, Wd, bd, out);
}